// Round 15
// baseline (2442.224 us; speedup 1.0000x reference)
//
#include <hip/hip_runtime.h>
#include <cstddef>
#include <cstdint>

#define NN 200000
#define NINT 25000     // nodes 0..24999 have children
#define NPAD 200064    // NN padded to 128

typedef _Float16 f16;
typedef __attribute__((ext_vector_type(8))) f16 f16x8;
typedef __attribute__((ext_vector_type(4))) float f32x4;

#define MFMA16(a,b,c) __builtin_amdgcn_mfma_f32_16x16x32_f16((a),(b),(c),0,0,0)

typedef __attribute__((address_space(1))) const uint32_t glb_u32;
typedef __attribute__((address_space(3))) uint32_t lds_u32;
#define GLD16(g,l) __builtin_amdgcn_global_load_lds((glb_u32*)(g), (lds_u32*)(l), 16, 0, 0)

union H8 { uint4 u; f16 f[8]; f16x8 v; };
union H4 { uint2 u; f16 f[4]; };
union F4 { float4 v; float f[4]; uint4 u; };

__device__ __forceinline__ float fsig(float v){ return __builtin_amdgcn_rcpf(1.f+__expf(-v)); }
__device__ __forceinline__ float ftanh(float v){ return 1.f-2.f*__builtin_amdgcn_rcpf(1.f+__expf(2.f*v)); }
// fp16 split-2: v = hi + lo/4096 + O(2^-22 |v|)
__device__ __forceinline__ void split2(float v, f16&h, f16&l){ h=(f16)v; l=(f16)((v-(float)h)*4096.f); }

// bijective XCD-chunking swizzle
__device__ __forceinline__ int xcd_swz(int bid, int nwg){
    int q = nwg >> 3, r = nwg & 7;
    int xcd = bid & 7, i = bid >> 3;
    return (xcd < r ? xcd*(q+1) : r*(q+1) + (xcd-r)*q) + i;
}

// FL (fragment layout) for activation arrays, rows padded to 128:
//   elem(row, k) -> f16 index ((row>>7)*32 + (k>>3))*1024 + (row&127)*8 + (k&7)
__device__ __forceinline__ size_t fl_idx(int row, int k){
    return ((size_t)(row >> 7)*32 + (k >> 3))*1024 + (size_t)(row & 127)*8 + (k & 7);
}

// ---------------------------------------------------------------------------
// Weight prep.
// iou (256x768): per ct(0..3, 64 d each): [kstep s][kb][wcol 0..191][8];
//   wcol = cg*96 + g*32 + sf*16 + cl, d = ct*64 + cg*32 + sf*16 + cl.
// ---------------------------------------------------------------------------
__global__ void split_w_iou(const float* __restrict__ src, f16* __restrict__ dh,
                            f16* __restrict__ dl)
{
    int e = blockIdx.x*256 + threadIdx.x;
    if (e >= 196608) return;
    int k = e / 768, n = e - k*768;
    f16 hh, ll; split2(src[e], hh, ll);
    int g = n >> 8, d = n & 255;
    int ct = d >> 6, cg = (d >> 5) & 1, sf = (d >> 4) & 1, cl = d & 15;
    int wcol = cg*96 + g*32 + sf*16 + cl;
    int s = k >> 5, kb = (k >> 3) & 3;
    size_t o = (((size_t)ct*8 + s)*4 + kb)*1536 + (size_t)wcol*8 + (k & 7);
    dh[o]=hh; dl[o]=ll;
}

// f (256x256): per ct(0..1, 128 cols each): [s][kb][wcol 0..127][8], wcol = n&127
__global__ void split_w_f(const float* __restrict__ src, f16* __restrict__ dh,
                          f16* __restrict__ dl)
{
    int e = blockIdx.x*256 + threadIdx.x;
    if (e >= 65536) return;
    int k = e / 256, n = e - k*256;
    f16 hh, ll; split2(src[e], hh, ll);
    int ct = n >> 7;
    int s = k >> 5, kb = (k >> 3) & 3;
    size_t o = (((size_t)ct*8 + s)*4 + kb)*1024 + (size_t)(n & 127)*8 + (k & 7);
    dh[o]=hh; dl[o]=ll;
}

// ---------------------------------------------------------------------------
// x (row-major fp32) -> FL hi/lo. 16 consecutive threads cover one row
// (coalesced 1KB reads); writes are 64B-chunked FL scatter.
// ---------------------------------------------------------------------------
__global__ void split_x_FL(const float* __restrict__ src,
                           f16* __restrict__ hi, f16* __restrict__ lo)
{
    long tid = (long)blockIdx.x*256 + threadIdx.x;
    if (tid >= (long)NPAD*16) return;
    int row = (int)(tid >> 4), u = (int)(tid & 15);
    int k0 = u*16;
    float v[16];
#pragma unroll
    for (int i = 0; i < 16; ++i) v[i] = 0.f;
    if (row < NN) {
        const float4* s = (const float4*)(src + (size_t)row*256 + k0);
#pragma unroll
        for (int i = 0; i < 4; ++i) { F4 t; t.v = s[i];
#pragma unroll
            for (int e = 0; e < 4; ++e) v[i*4+e] = t.f[e]; }
    }
#pragma unroll
    for (int half = 0; half < 2; ++half) {
        H8 ph, pl;
#pragma unroll
        for (int e = 0; e < 8; ++e) split2(v[half*8+e], ph.f[e], pl.f[e]);
        size_t o = ((size_t)(row >> 7)*32 + u*2 + half)*1024 + (size_t)(row & 127)*8;
        *(uint4*)(hi + o) = ph.u;
        *(uint4*)(lo + o) = pl.u;
    }
}

// ---------------------------------------------------------------------------
// ht[p] = sum_children h (fp32 in) -> FL hi/lo at row (p - tstart)
// ---------------------------------------------------------------------------
__global__ void ht_sum_FL(const float* __restrict__ h,
                          f16* __restrict__ hth, f16* __restrict__ htl,
                          int ps, int pe, int tstart)
{
    int idx = blockIdx.x*256 + threadIdx.x;
    int p = ps + (idx >> 6);
    if (p >= pe) return;
    int dq = (idx & 63) << 2;
    F4 s; s.v = (float4){0,0,0,0};
    int c0 = p*8 + 1;
#pragma unroll
    for (int j = 0; j < 8; ++j) {
        int child = c0 + j;
        if (child < NN) {
            F4 v; v.v = *(const float4*)(h + (size_t)child*256 + dq);
#pragma unroll
            for (int e = 0; e < 4; ++e) s.f[e] += v.f[e];
        }
    }
    H4 sh, sl;
#pragma unroll
    for (int e = 0; e < 4; ++e) split2(s.f[e], sh.f[e], sl.f[e]);
    size_t o = fl_idx(p - tstart, dq);
    *(uint2*)(hth + o) = sh.u;
    *(uint2*)(htl + o) = sl.u;
}

// ---------------------------------------------------------------------------
// iou_gemm<MODE>: m97-style global_load_lds GEMM vs W_iou (+U_iou), N=192.
//   MODE 0: childless (P=8, acts=x FL).  MODE 1: internal (P=16, x then ht).
// Block 512thr = 8 waves (ng=wv&3: 32-node group, cg=wv>>2: 96-wcol group);
// tile 128 nodes x 192 wcols (3 gates x 64 d), ct 0..3 covers d 0..255.
// Per wave per K-step: 4 act + 12 weight ds_read_b128 -> 36 MFMA.
// LDS 80KB -> exactly 2 blocks/CU. 40 GLD16 chunks/step, 5 per wave.
// ---------------------------------------------------------------------------
template<int MODE>
__launch_bounds__(512, 4)
__global__ void iou_gemm(const f16* __restrict__ xh, const f16* __restrict__ xl,
                         const f16* __restrict__ hth, const f16* __restrict__ htl,
                         const f16* __restrict__ wih, const f16* __restrict__ wil,
                         const f16* __restrict__ uih, const f16* __restrict__ uil,
                         const float* __restrict__ b_iou, const float* __restrict__ fcR,
                         float* __restrict__ cW, float* __restrict__ hW,
                         f16* __restrict__ hfh, f16* __restrict__ hfl,
                         int tstart, int nlo, int nhi)
{
    __shared__ f16 AH[2][4096], AL[2][4096], WH[2][6144], WL[2][6144];  // 80KB

    const int work = xcd_swz(blockIdx.x, gridDim.x);
    const int tile = work >> 2, ct = work & 3;
    const int lane = threadIdx.x & 63, wv = threadIdx.x >> 6;
    const int c15 = lane & 15, qq = lane >> 4;
    const int ng = wv & 3, cg = wv >> 2;
    const int tbase = tstart + tile*128;
    const float INV = 1.f/4096.f;

    f32x4 aH[2][6], aL[2][6];
#pragma unroll
    for (int m = 0; m < 2; ++m)
#pragma unroll
        for (int n = 0; n < 6; ++n) { aH[m][n] = (f32x4){0,0,0,0}; aL[m][n] = (f32x4){0,0,0,0}; }

    const int P = (MODE == 1) ? 16 : 8;

    auto ISSUE = [&](int p, int nb){
        const int kstep = p & 7, phase = p >> 3;
        const f16 *ab_h, *ab_l;
        if (phase == 0) {
            size_t ab = (size_t)(tbase >> 7)*32768 + (size_t)kstep*4096;
            ab_h = xh + ab; ab_l = xl + ab;
        } else {
            size_t ab = (size_t)tile*32768 + (size_t)kstep*4096;
            ab_h = hth + ab; ab_l = htl + ab;
        }
        size_t wb = ((size_t)ct*8 + kstep)*6144;
        const f16* wb_h = ((phase == 0) ? wih : uih) + wb;
        const f16* wb_l = ((phase == 0) ? wil : uil) + wb;
#pragma unroll
        for (int i = 0; i < 5; ++i) {
            int cid = wv*5 + i;                        // 0..39 exact
            if (cid < 8)       GLD16(ab_h + cid*512 + lane*8,      &AH[nb][cid*512]);
            else if (cid < 16) GLD16(ab_l + (cid-8)*512 + lane*8,  &AL[nb][(cid-8)*512]);
            else if (cid < 28) GLD16(wb_h + (cid-16)*512 + lane*8, &WH[nb][(cid-16)*512]);
            else               GLD16(wb_l + (cid-28)*512 + lane*8, &WL[nb][(cid-28)*512]);
        }
    };

    ISSUE(0, 0);
    __syncthreads();
    int buf = 0;
    for (int p = 0; p < P; ++p) {
        if (p + 1 < P) ISSUE(p + 1, buf ^ 1);
        {
            const int a0 = (qq*128 + ng*32 + c15)*8;
            f16x8 b0h = *(const f16x8*)&AH[buf][a0];
            f16x8 b0l = *(const f16x8*)&AL[buf][a0];
            f16x8 b1h = *(const f16x8*)&AH[buf][a0 + 128];
            f16x8 b1l = *(const f16x8*)&AL[buf][a0 + 128];
#pragma unroll
            for (int n = 0; n < 6; ++n) {              // n = g*2 + sf
                const int wo = (qq*192 + cg*96 + n*16 + c15)*8;
                f16x8 gh = *(const f16x8*)&WH[buf][wo];
                f16x8 gl = *(const f16x8*)&WL[buf][wo];
                aH[0][n] = MFMA16(gh, b0h, aH[0][n]);
                aL[0][n] = MFMA16(gh, b0l, aL[0][n]);
                aL[0][n] = MFMA16(gl, b0h, aL[0][n]);
                aH[1][n] = MFMA16(gh, b1h, aH[1][n]);
                aL[1][n] = MFMA16(gh, b1l, aL[1][n]);
                aL[1][n] = MFMA16(gl, b1h, aL[1][n]);
            }
        }
        __syncthreads();
        buf ^= 1;
    }

    // ---- LSTM epilogue ----  (n = g*2+sf: ig=acc[sf], og=acc[2+sf], ug=acc[4+sf])
#pragma unroll
    for (int m = 0; m < 2; ++m) {
        const int node = tbase + ng*32 + m*16 + c15;
        if (node >= nlo && node < nhi) {
#pragma unroll
            for (int sf = 0; sf < 2; ++sf) {
                const int d0 = ct*64 + cg*32 + sf*16 + qq*4;
                F4 bi, bo, bu, fcv, cn, hn; H4 sh, sl;
                bi.v = *(const float4*)(b_iou + d0);
                bo.v = *(const float4*)(b_iou + 256 + d0);
                bu.v = *(const float4*)(b_iou + 512 + d0);
                fcv.v = (float4){0,0,0,0};
                if (MODE == 1) fcv.v = *(const float4*)(fcR + (size_t)(node - tstart)*256 + d0);
#pragma unroll
                for (int j = 0; j < 4; ++j) {
                    float ig = aH[m][0+sf][j] + aL[m][0+sf][j]*INV + bi.f[j];
                    float og = aH[m][2+sf][j] + aL[m][2+sf][j]*INV + bo.f[j];
                    float ug = aH[m][4+sf][j] + aL[m][4+sf][j]*INV + bu.f[j];
                    float cc = fsig(ig)*ftanh(ug) + fcv.f[j];
                    cn.f[j] = cc;
                    float hh = fsig(og)*ftanh(cc);
                    hn.f[j] = hh;
                    split2(hh, sh.f[j], sl.f[j]);
                }
                const size_t no = (size_t)node*256 + d0;
                *(float4*)(cW + no) = cn.v;
                *(float4*)(hW + no) = hn.v;
                if (node >= 1) {
                    size_t o = fl_idx(node - 1, d0);
                    *(uint2*)(hfh + o) = sh.u;
                    *(uint2*)(hfl + o) = sl.u;
                }
            }
        }
    }
}

// ---------------------------------------------------------------------------
// f_gemm<FM>: same structure vs 256-col weight (K=256, P=8), N=128.
// Block 512thr = 8 waves (ng=wv&3: 32 rows, cg=wv>>2: 64 cols);
// tile 128 rows x 128 cols; ct 0..1. 64KB LDS -> 2 blocks/CU.
// 32 GLD16/step, 4 per wave. Per wave: 4 act + 8 weight ds_read -> 24 MFMA.
//   FM 0: xf = x@W_f + b_f (acts = x FL, node-indexed, shift 0)
//   FM 1: child pass (acts = h FL, (node-1)-indexed, shift 1):
//         f = sigm(acc + xf[par]); fc[par - tstart_p] = shfl-sum f*c
// ---------------------------------------------------------------------------
template<int FM>
__launch_bounds__(512, 4)
__global__ void f_gemm(const f16* __restrict__ ah_, const f16* __restrict__ al_,
                       const f16* __restrict__ wh_, const f16* __restrict__ wl_,
                       const float* __restrict__ b_f,
                       const float* __restrict__ xfR, const float* __restrict__ cR,
                       float* __restrict__ outW,
                       int rstart, int nlo, int nhi, int tstart_p)
{
    __shared__ f16 AH[2][4096], AL[2][4096], WH[2][4096], WL[2][4096];  // 64KB

    const int work = xcd_swz(blockIdx.x, gridDim.x);
    const int tile = work >> 1, ct = work & 1;
    const int lane = threadIdx.x & 63, wv = threadIdx.x >> 6;
    const int c15 = lane & 15, qq = lane >> 4;
    const int ng = wv & 3, cg = wv >> 2;
    const int rbase = rstart + tile*128;
    const float INV = 1.f/4096.f;

    f32x4 aH[2][4], aL[2][4];
#pragma unroll
    for (int m = 0; m < 2; ++m)
#pragma unroll
        for (int u = 0; u < 4; ++u) { aH[m][u] = (f32x4){0,0,0,0}; aL[m][u] = (f32x4){0,0,0,0}; }

    auto ISSUE = [&](int kstep, int nb){
        size_t ab = (size_t)(rbase >> 7)*32768 + (size_t)kstep*4096;
        size_t wb = ((size_t)ct*8 + kstep)*4096;
#pragma unroll
        for (int i = 0; i < 4; ++i) {
            int cid = wv*4 + i;                        // 0..31 exact
            if (cid < 8)       GLD16(ah_ + ab + cid*512 + lane*8,      &AH[nb][cid*512]);
            else if (cid < 16) GLD16(al_ + ab + (cid-8)*512 + lane*8,  &AL[nb][(cid-8)*512]);
            else if (cid < 24) GLD16(wh_ + wb + (cid-16)*512 + lane*8, &WH[nb][(cid-16)*512]);
            else               GLD16(wl_ + wb + (cid-24)*512 + lane*8, &WL[nb][(cid-24)*512]);
        }
    };

    ISSUE(0, 0);
    __syncthreads();
    int buf = 0;
    for (int p = 0; p < 8; ++p) {
        if (p + 1 < 8) ISSUE(p + 1, buf ^ 1);
        {
            const int a0 = (qq*128 + ng*32 + c15)*8;
            f16x8 b0h = *(const f16x8*)&AH[buf][a0];
            f16x8 b0l = *(const f16x8*)&AL[buf][a0];
            f16x8 b1h = *(const f16x8*)&AH[buf][a0 + 128];
            f16x8 b1l = *(const f16x8*)&AL[buf][a0 + 128];
#pragma unroll
            for (int u = 0; u < 4; ++u) {
                const int wo = (qq*128 + cg*64 + u*16 + c15)*8;
                f16x8 gh = *(const f16x8*)&WH[buf][wo];
                f16x8 gl = *(const f16x8*)&WL[buf][wo];
                aH[0][u] = MFMA16(gh, b0h, aH[0][u]);
                aL[0][u] = MFMA16(gh, b0l, aL[0][u]);
                aL[0][u] = MFMA16(gl, b0h, aL[0][u]);
                aH[1][u] = MFMA16(gh, b1h, aH[1][u]);
                aL[1][u] = MFMA16(gh, b1l, aL[1][u]);
                aL[1][u] = MFMA16(gl, b1h, aL[1][u]);
            }
        }
        __syncthreads();
        buf ^= 1;
    }

#pragma unroll
    for (int m = 0; m < 2; ++m) {
        const int node = rbase + ng*32 + m*16 + c15 + (FM ? 1 : 0);
        const bool nv = (node >= nlo) && (node < nhi);
#pragma unroll
        for (int u = 0; u < 4; ++u) {
            const int d0 = ct*128 + cg*64 + u*16 + qq*4;
            if (FM == 0) {
                if (nv) {
                    F4 bf; bf.v = *(const float4*)(b_f + d0);
                    F4 o;
#pragma unroll
                    for (int j = 0; j < 4; ++j)
                        o.f[j] = aH[m][u][j] + aL[m][u][j]*INV + bf.f[j];
                    *(float4*)(outW + (size_t)node*256 + d0) = o.v;
                }
            } else {
                const int par = (node - 1) >> 3;
                F4 q; q.v = (float4){0,0,0,0};
                if (nv) {
                    F4 xf4, c4;
                    xf4.v = *(const float4*)(xfR + (size_t)par*256 + d0);
                    c4.v  = *(const float4*)(cR + (size_t)node*256 + d0);
#pragma unroll
                    for (int j = 0; j < 4; ++j) {
                        float f = fsig(aH[m][u][j] + aL[m][u][j]*INV + xf4.f[j]);
                        q.f[j] = f * c4.f[j];
                    }
                }
#pragma unroll
                for (int j = 0; j < 4; ++j) {
                    q.f[j] += __shfl_xor(q.f[j], 1);
                    q.f[j] += __shfl_xor(q.f[j], 2);
                    q.f[j] += __shfl_xor(q.f[j], 4);
                }
                if (((c15 & 7) == 0) && nv)
                    *(float4*)(outW + (size_t)(par - tstart_p)*256 + d0) = q.v;
            }
        }
    }
}

// ---------------------------------------------------------------------------

extern "C" void kernel_launch(void* const* d_in, const int* in_sizes, int n_in,
                              void* d_out, int out_size, void* d_ws, size_t ws_size,
                              hipStream_t stream)
{
    const float* x     = (const float*)d_in[0];
    const float* W_iou = (const float*)d_in[1];
    const float* U_iou = (const float*)d_in[2];
    const float* b_iou = (const float*)d_in[3];
    const float* W_f   = (const float*)d_in[4];
    const float* U_f   = (const float*)d_in[5];
    const float* b_f   = (const float*)d_in[6];

    float* h  = (float*)d_out;
    float* xf = (float*)d_out;   // rows 0..24999 alias (proven R9-R12 ordering)

    char* p = (char*)d_ws;
    float* c   = (float*)p;  p += (size_t)NN*256*4;
    float* fc  = (float*)p;  p += (size_t)20480*256*4;
    f16* hthF = (f16*)p;     p += (size_t)20480*256*2;
    f16* htlF = (f16*)p;     p += (size_t)20480*256*2;
    f16* xhF = (f16*)p;      p += (size_t)NPAD*256*2;
    f16* xlF = (f16*)p;      p += (size_t)NPAD*256*2;
    f16* hhF = (f16*)p;      p += (size_t)NPAD*256*2;
    f16* hlF = (f16*)p;      p += (size_t)NPAD*256*2;
    f16* wih = (f16*)p;  p += 196608*2;
    f16* wil = (f16*)p;  p += 196608*2;
    f16* uih = (f16*)p;  p += 196608*2;
    f16* uil = (f16*)p;  p += 196608*2;
    f16* wfh = (f16*)p;  p += 65536*2;
    f16* wfl = (f16*)p;  p += 65536*2;
    f16* ufh = (f16*)p;  p += 65536*2;
    f16* ufl = (f16*)p;  p += 65536*2;

    split_w_iou<<<768, 256, 0, stream>>>(W_iou, wih, wil);
    split_w_iou<<<768, 256, 0, stream>>>(U_iou, uih, uil);
    split_w_f<<<256, 256, 0, stream>>>(W_f, wfh, wfl);
    split_w_f<<<256, 256, 0, stream>>>(U_f, ufh, ufl);
    split_x_FL<<<(int)(((long)NPAD*16 + 255)/256), 256, 0, stream>>>(x, xhF, xlF);

    const int S_[8] = {0, 1, 9, 73, 585, 4681, 37449, 200000};
    auto cdiv = [](int a, int b){ return (a + b - 1) / b; };

    // xf = x @ W_f + b_f for internal nodes (into d_out rows 0..24999)
    {
        int nt = cdiv(NINT, 128);
        f_gemm<0><<<nt*2, 512, 0, stream>>>(xhF, xlF, wfh, wfl, b_f,
            nullptr, nullptr, xf, 0, 0, NINT, 0);
    }
    // childless nodes 25000..199999: full LSTM, fc = 0
    {
        int tstart = 24960;                       // 128-aligned
        int nt = cdiv(NN - tstart, 128);
        iou_gemm<0><<<nt*4, 512, 0, stream>>>(xhF, xlF, nullptr, nullptr,
            wih, wil, nullptr, nullptr, b_iou, nullptr,
            c, h, hhF, hlF, tstart, NINT, NN);
    }
    // levels 5..0
    for (int l = 5; l >= 0; --l) {
        int ps = S_[l];
        int pe = (S_[l+1] < NINT) ? S_[l+1] : NINT;
        int cs = S_[l+1], ce = S_[l+2];
        int tsp = (ps >> 7) << 7;

        // child pass: acts = h FL ((node-1)-indexed)
        {
            int rstart = ((cs - 1) >> 7) << 7;
            int nt = cdiv((ce - 1) - rstart, 128);
            f_gemm<1><<<nt*2, 512, 0, stream>>>(hhF, hlF, ufh, ufl, nullptr,
                xf, c, fc, rstart, cs, ce, tsp);
        }
        // ht segment-sum -> FL (rows p - tsp)
        ht_sum_FL<<<cdiv((pe - ps)*64, 256), 256, 0, stream>>>(h, hthF, htlF, ps, pe, tsp);
        // parent pass: phase0 x@W_iou, phase1 ht@U_iou, + fc
        {
            int nt = cdiv(pe - tsp, 128);
            iou_gemm<1><<<nt*4, 512, 0, stream>>>(xhF, xlF, hthF, htlF,
                wih, wil, uih, uil, b_iou, fc,
                c, h, hhF, hlF, tsp, ps, pe);
        }
    }
}

// Round 16
// 906.639 us; speedup vs baseline: 2.6937x; 2.6937x over previous
//
#include <hip/hip_runtime.h>
#include <cstddef>
#include <cstdint>

#define NN 200000
#define NINT 25000     // nodes 0..24999 have children
#define NPAD 200064    // NN padded to 128

typedef _Float16 f16;
typedef __attribute__((ext_vector_type(8))) f16 f16x8;
typedef __attribute__((ext_vector_type(4))) float f32x4;

#define MFMA16(a,b,c) __builtin_amdgcn_mfma_f32_16x16x32_f16((a),(b),(c),0,0,0)

typedef __attribute__((address_space(1))) const uint32_t glb_u32;
typedef __attribute__((address_space(3))) uint32_t lds_u32;
#define GLD16(g,l) __builtin_amdgcn_global_load_lds((glb_u32*)(g), (lds_u32*)(l), 16, 0, 0)

union H8 { uint4 u; f16 f[8]; f16x8 v; };
union H4 { uint2 u; f16 f[4]; };
union F4 { float4 v; float f[4]; uint4 u; };

__device__ __forceinline__ float fsig(float v){ return __builtin_amdgcn_rcpf(1.f+__expf(-v)); }
__device__ __forceinline__ float ftanh(float v){ return 1.f-2.f*__builtin_amdgcn_rcpf(1.f+__expf(2.f*v)); }
// fp16 split-2: v = hi + lo/4096 + O(2^-22 |v|)
__device__ __forceinline__ void split2(float v, f16&h, f16&l){ h=(f16)v; l=(f16)((v-(float)h)*4096.f); }

// bijective XCD-chunking swizzle
__device__ __forceinline__ int xcd_swz(int bid, int nwg){
    int q = nwg >> 3, r = nwg & 7;
    int xcd = bid & 7, i = bid >> 3;
    return (xcd < r ? xcd*(q+1) : r*(q+1) + (xcd-r)*q) + i;
}

// FL (fragment layout) for activation arrays, rows padded to 128:
//   elem(row, k) -> f16 index ((row>>7)*32 + (k>>3))*1024 + (row&127)*8 + (k&7)
__device__ __forceinline__ size_t fl_idx(int row, int k){
    return ((size_t)(row >> 7)*32 + (k >> 3))*1024 + (size_t)(row & 127)*8 + (k & 7);
}

// ---------------------------------------------------------------------------
// Prep: weights -> staged-chunk layout (contiguous 6KB/4KB per ct per K-step)
// iou (256x768): per ct(0..7): [kstep][kc][wcol 0..95][8], wcol=cg*48+g*16+cl,
//                d = ct*32 + cg*16 + cl
// ---------------------------------------------------------------------------
__global__ void split_w_iou(const float* __restrict__ src, f16* __restrict__ dh,
                            f16* __restrict__ dl)
{
    int e = blockIdx.x*256 + threadIdx.x;
    if (e >= 196608) return;
    int k = e / 768, n = e - k*768;
    f16 hh, ll; split2(src[e], hh, ll);
    int g = n >> 8, d = n & 255;
    int ct = d >> 5, cg = (d >> 4) & 1, cl = d & 15;
    int wcol = cg*48 + g*16 + cl;
    size_t o = (size_t)ct*24576 + (size_t)(((k>>5)*4 + ((k>>3)&3))*96 + wcol)*8 + (k&7);
    dh[o]=hh; dl[o]=ll;
}

// f (256x256): per ct(0..3): [kstep][kc][wcol 0..63][8], wcol=cg*32+sl*16+cl
__global__ void split_w_f(const float* __restrict__ src, f16* __restrict__ dh,
                          f16* __restrict__ dl)
{
    int e = blockIdx.x*256 + threadIdx.x;
    if (e >= 65536) return;
    int k = e / 256, n = e - k*256;
    f16 hh, ll; split2(src[e], hh, ll);
    int ct = n >> 6, cg = (n >> 5) & 1, sl = (n >> 4) & 1, cl = n & 15;
    int wcol = cg*32 + sl*16 + cl;
    size_t o = (size_t)ct*16384 + (size_t)(((k>>5)*4 + ((k>>3)&3))*64 + wcol)*8 + (k&7);
    dh[o]=hh; dl[o]=ll;
}

// ---------------------------------------------------------------------------
// x (row-major fp32) -> FL hi/lo. 16 consecutive threads cover one row
// (coalesced 1KB reads); writes are 64B-chunked FL scatter.
// ---------------------------------------------------------------------------
__global__ void split_x_FL(const float* __restrict__ src,
                           f16* __restrict__ hi, f16* __restrict__ lo)
{
    long tid = (long)blockIdx.x*256 + threadIdx.x;
    if (tid >= (long)NPAD*16) return;
    int row = (int)(tid >> 4), u = (int)(tid & 15);
    int k0 = u*16;
    float v[16];
#pragma unroll
    for (int i = 0; i < 16; ++i) v[i] = 0.f;
    if (row < NN) {
        const float4* s = (const float4*)(src + (size_t)row*256 + k0);
#pragma unroll
        for (int i = 0; i < 4; ++i) { F4 t; t.v = s[i];
#pragma unroll
            for (int e = 0; e < 4; ++e) v[i*4+e] = t.f[e]; }
    }
#pragma unroll
    for (int half = 0; half < 2; ++half) {
        H8 ph, pl;
#pragma unroll
        for (int e = 0; e < 8; ++e) split2(v[half*8+e], ph.f[e], pl.f[e]);
        size_t o = ((size_t)(row >> 7)*32 + u*2 + half)*1024 + (size_t)(row & 127)*8;
        *(uint4*)(hi + o) = ph.u;
        *(uint4*)(lo + o) = pl.u;
    }
}

// ---------------------------------------------------------------------------
// ht[p] = sum_children h (fp32 in) -> FL hi/lo at row (p - tstart)
// ---------------------------------------------------------------------------
__global__ void ht_sum_FL(const float* __restrict__ h,
                          f16* __restrict__ hth, f16* __restrict__ htl,
                          int ps, int pe, int tstart)
{
    int idx = blockIdx.x*256 + threadIdx.x;
    int p = ps + (idx >> 6);
    if (p >= pe) return;
    int dq = (idx & 63) << 2;
    F4 s; s.v = (float4){0,0,0,0};
    int c0 = p*8 + 1;
#pragma unroll
    for (int j = 0; j < 8; ++j) {
        int child = c0 + j;
        if (child < NN) {
            F4 v; v.v = *(const float4*)(h + (size_t)child*256 + dq);
#pragma unroll
            for (int e = 0; e < 4; ++e) s.f[e] += v.f[e];
        }
    }
    H4 sh, sl;
#pragma unroll
    for (int e = 0; e < 4; ++e) split2(s.f[e], sh.f[e], sl.f[e]);
    size_t o = fl_idx(p - tstart, dq);
    *(uint2*)(hth + o) = sh.u;
    *(uint2*)(htl + o) = sl.u;
}

// ---------------------------------------------------------------------------
// iou_gemm<MODE>: m97-style global_load_lds GEMM vs W_iou (+U_iou).
//   MODE 0: childless (P=8, acts=x FL).  MODE 1: internal (P=16, x then ht).
// Block 512thr = 8 waves (ng=wv&3: 32-node group, cg=wv>>2: 48-col group);
// tile 128 nodes x 96 cols (3 gates x 32 d), ct 0..7 covers d 0..255.
// Epilogue: full LSTM -> c, h (fp32) + h-split FL (row node-1).
// ---------------------------------------------------------------------------
template<int MODE>
__launch_bounds__(512, 4)
__global__ void iou_gemm(const f16* __restrict__ xh, const f16* __restrict__ xl,
                         const f16* __restrict__ hth, const f16* __restrict__ htl,
                         const f16* __restrict__ wih, const f16* __restrict__ wil,
                         const f16* __restrict__ uih, const f16* __restrict__ uil,
                         const float* __restrict__ b_iou, const float* __restrict__ fcR,
                         float* __restrict__ cW, float* __restrict__ hW,
                         f16* __restrict__ hfh, f16* __restrict__ hfl,
                         int tstart, int nlo, int nhi)
{
    __shared__ f16 AH[2][4096], AL[2][4096], WH[2][3072], WL[2][3072];  // 56KB

    const int work = xcd_swz(blockIdx.x, gridDim.x);
    const int tile = work >> 3, ct = work & 7;
    const int lane = threadIdx.x & 63, wv = threadIdx.x >> 6;
    const int c15 = lane & 15, qq = lane >> 4;
    const int ng = wv & 3, cg = wv >> 2;
    const int tbase = tstart + tile*128;
    const float INV = 1.f/4096.f;

    f32x4 aH[2][3], aL[2][3];
#pragma unroll
    for (int m = 0; m < 2; ++m)
#pragma unroll
        for (int g = 0; g < 3; ++g) { aH[m][g] = (f32x4){0,0,0,0}; aL[m][g] = (f32x4){0,0,0,0}; }

    const int P = (MODE == 1) ? 16 : 8;

    auto ISSUE = [&](int p, int nb){
        const int kstep = p & 7, phase = p >> 3;
        const f16 *ab_h, *ab_l, *wb_h, *wb_l;
        if (phase == 0) {
            size_t ab = (size_t)(tbase >> 7)*32768 + (size_t)kstep*4096;
            ab_h = xh + ab; ab_l = xl + ab;
        } else {
            size_t ab = (size_t)tile*32768 + (size_t)kstep*4096;
            ab_h = hth + ab; ab_l = htl + ab;
        }
        size_t wb = (size_t)ct*24576 + (size_t)kstep*3072;
        wb_h = ((phase == 0) ? wih : uih) + wb;
        wb_l = ((phase == 0) ? wil : uil) + wb;
        for (int i = 0; i < 4; ++i) {
            int cid = wv + i*8;
            if (cid >= 28) break;
            if (cid < 8)       GLD16(ab_h + cid*512 + lane*8,      &AH[nb][cid*512]);
            else if (cid < 16) GLD16(ab_l + (cid-8)*512 + lane*8,  &AL[nb][(cid-8)*512]);
            else if (cid < 22) GLD16(wb_h + (cid-16)*512 + lane*8, &WH[nb][(cid-16)*512]);
            else               GLD16(wb_l + (cid-22)*512 + lane*8, &WL[nb][(cid-22)*512]);
        }
    };

    ISSUE(0, 0);
    __syncthreads();
    int buf = 0;
    for (int p = 0; p < P; ++p) {
        if (p + 1 < P) ISSUE(p + 1, buf ^ 1);
        const int a0 = (qq*128 + ng*32 + c15)*8;
        f16x8 b0h = *(const f16x8*)&AH[buf][a0];
        f16x8 b0l = *(const f16x8*)&AL[buf][a0];
        f16x8 b1h = *(const f16x8*)&AH[buf][a0 + 128];
        f16x8 b1l = *(const f16x8*)&AL[buf][a0 + 128];
#pragma unroll
        for (int g = 0; g < 3; ++g) {
            const int wo = (qq*96 + cg*48 + g*16 + c15)*8;
            f16x8 gh = *(const f16x8*)&WH[buf][wo];
            f16x8 gl = *(const f16x8*)&WL[buf][wo];
            aH[0][g] = MFMA16(gh, b0h, aH[0][g]);
            aL[0][g] = MFMA16(gh, b0l, aL[0][g]);
            aL[0][g] = MFMA16(gl, b0h, aL[0][g]);
            aH[1][g] = MFMA16(gh, b1h, aH[1][g]);
            aL[1][g] = MFMA16(gh, b1l, aL[1][g]);
            aL[1][g] = MFMA16(gl, b1h, aL[1][g]);
        }
        __syncthreads();
        buf ^= 1;
    }

    // ---- LSTM epilogue ----
    const int d0 = ct*32 + cg*16 + qq*4;
    F4 bi, bo, bu;
    bi.v = *(const float4*)(b_iou + d0);
    bo.v = *(const float4*)(b_iou + 256 + d0);
    bu.v = *(const float4*)(b_iou + 512 + d0);
#pragma unroll
    for (int m = 0; m < 2; ++m) {
        const int node = tbase + ng*32 + m*16 + c15;
        if (node >= nlo && node < nhi) {
            F4 fcv; fcv.v = (float4){0,0,0,0};
            if (MODE == 1) fcv.v = *(const float4*)(fcR + (size_t)(node - tstart)*256 + d0);
            F4 cn, hn; H4 sh, sl;
#pragma unroll
            for (int j = 0; j < 4; ++j) {
                float ig = aH[m][0][j] + aL[m][0][j]*INV + bi.f[j];
                float og = aH[m][1][j] + aL[m][1][j]*INV + bo.f[j];
                float ug = aH[m][2][j] + aL[m][2][j]*INV + bu.f[j];
                float cc = fsig(ig)*ftanh(ug) + fcv.f[j];
                cn.f[j] = cc;
                float hh = fsig(og)*ftanh(cc);
                hn.f[j] = hh;
                split2(hh, sh.f[j], sl.f[j]);
            }
            const size_t no = (size_t)node*256 + d0;
            *(float4*)(cW + no) = cn.v;
            *(float4*)(hW + no) = hn.v;
            if (node >= 1) {
                size_t o = fl_idx(node - 1, d0);
                *(uint2*)(hfh + o) = sh.u;
                *(uint2*)(hfl + o) = sl.u;
            }
        }
    }
}

// ---------------------------------------------------------------------------
// f_gemm<FM>: same structure vs 256-col weight (K=256, P=8).
// Block 512thr = 8 waves (ng=wv&3: 32 rows, cg=wv>>2: 32 cols);
// tile 128 rows x 64 cols; ct 0..3.
//   FM 0: xf = x@W_f + b_f (acts = x FL, node-indexed, shift 0)
//   FM 1: child pass (acts = h FL, (node-1)-indexed, shift 1):
//         f = sigm(acc + xf[par]); fc[par - tstart_p] = shfl-sum f*c
// ---------------------------------------------------------------------------
template<int FM>
__launch_bounds__(512, 4)
__global__ void f_gemm(const f16* __restrict__ ah_, const f16* __restrict__ al_,
                       const f16* __restrict__ wh_, const f16* __restrict__ wl_,
                       const float* __restrict__ b_f,
                       const float* __restrict__ xfR, const float* __restrict__ cR,
                       float* __restrict__ outW,
                       int rstart, int nlo, int nhi, int tstart_p)
{
    __shared__ f16 AH[2][4096], AL[2][4096], WH[2][2048], WL[2][2048];  // 48KB

    const int work = xcd_swz(blockIdx.x, gridDim.x);
    const int tile = work >> 2, ct = work & 3;
    const int lane = threadIdx.x & 63, wv = threadIdx.x >> 6;
    const int c15 = lane & 15, qq = lane >> 4;
    const int ng = wv & 3, cg = wv >> 2;
    const int rbase = rstart + tile*128;
    const float INV = 1.f/4096.f;

    f32x4 aH[2][2], aL[2][2];
#pragma unroll
    for (int m = 0; m < 2; ++m)
#pragma unroll
        for (int s = 0; s < 2; ++s) { aH[m][s] = (f32x4){0,0,0,0}; aL[m][s] = (f32x4){0,0,0,0}; }

    auto ISSUE = [&](int kstep, int nb){
        size_t ab = (size_t)(rbase >> 7)*32768 + (size_t)kstep*4096;
        size_t wb = (size_t)ct*16384 + (size_t)kstep*2048;
        for (int i = 0; i < 3; ++i) {
            int cid = wv + i*8;
            if (cid >= 24) break;
            if (cid < 8)       GLD16(ah_ + ab + cid*512 + lane*8,      &AH[nb][cid*512]);
            else if (cid < 16) GLD16(al_ + ab + (cid-8)*512 + lane*8,  &AL[nb][(cid-8)*512]);
            else if (cid < 20) GLD16(wh_ + wb + (cid-16)*512 + lane*8, &WH[nb][(cid-16)*512]);
            else               GLD16(wl_ + wb + (cid-20)*512 + lane*8, &WL[nb][(cid-20)*512]);
        }
    };

    ISSUE(0, 0);
    __syncthreads();
    int buf = 0;
    for (int p = 0; p < 8; ++p) {
        if (p + 1 < 8) ISSUE(p + 1, buf ^ 1);
        const int a0 = (qq*128 + ng*32 + c15)*8;
        f16x8 b0h = *(const f16x8*)&AH[buf][a0];
        f16x8 b0l = *(const f16x8*)&AL[buf][a0];
        f16x8 b1h = *(const f16x8*)&AH[buf][a0 + 128];
        f16x8 b1l = *(const f16x8*)&AL[buf][a0 + 128];
#pragma unroll
        for (int s = 0; s < 2; ++s) {
            const int wo = (qq*64 + cg*32 + s*16 + c15)*8;
            f16x8 gh = *(const f16x8*)&WH[buf][wo];
            f16x8 gl = *(const f16x8*)&WL[buf][wo];
            aH[0][s] = MFMA16(gh, b0h, aH[0][s]);
            aL[0][s] = MFMA16(gh, b0l, aL[0][s]);
            aL[0][s] = MFMA16(gl, b0h, aL[0][s]);
            aH[1][s] = MFMA16(gh, b1h, aH[1][s]);
            aL[1][s] = MFMA16(gh, b1l, aL[1][s]);
            aL[1][s] = MFMA16(gl, b1h, aL[1][s]);
        }
        __syncthreads();
        buf ^= 1;
    }

#pragma unroll
    for (int m = 0; m < 2; ++m) {
        const int node = rbase + ng*32 + m*16 + c15 + (FM ? 1 : 0);
        const bool nv = (node >= nlo) && (node < nhi);
#pragma unroll
        for (int s = 0; s < 2; ++s) {
            const int d0 = ct*64 + cg*32 + s*16 + qq*4;
            if (FM == 0) {
                if (nv) {
                    F4 bf; bf.v = *(const float4*)(b_f + d0);
                    F4 o;
#pragma unroll
                    for (int j = 0; j < 4; ++j)
                        o.f[j] = aH[m][s][j] + aL[m][s][j]*INV + bf.f[j];
                    *(float4*)(outW + (size_t)node*256 + d0) = o.v;
                }
            } else {
                const int par = (node - 1) >> 3;
                F4 q; q.v = (float4){0,0,0,0};
                if (nv) {
                    F4 xf4, c4;
                    xf4.v = *(const float4*)(xfR + (size_t)par*256 + d0);
                    c4.v  = *(const float4*)(cR + (size_t)node*256 + d0);
#pragma unroll
                    for (int j = 0; j < 4; ++j) {
                        float f = fsig(aH[m][s][j] + aL[m][s][j]*INV + xf4.f[j]);
                        q.f[j] = f * c4.f[j];
                    }
                }
#pragma unroll
                for (int j = 0; j < 4; ++j) {
                    q.f[j] += __shfl_xor(q.f[j], 1);
                    q.f[j] += __shfl_xor(q.f[j], 2);
                    q.f[j] += __shfl_xor(q.f[j], 4);
                }
                if (((c15 & 7) == 0) && nv)
                    *(float4*)(outW + (size_t)(par - tstart_p)*256 + d0) = q.v;
            }
        }
    }
}

// ---------------------------------------------------------------------------

extern "C" void kernel_launch(void* const* d_in, const int* in_sizes, int n_in,
                              void* d_out, int out_size, void* d_ws, size_t ws_size,
                              hipStream_t stream)
{
    const float* x     = (const float*)d_in[0];
    const float* W_iou = (const float*)d_in[1];
    const float* U_iou = (const float*)d_in[2];
    const float* b_iou = (const float*)d_in[3];
    const float* W_f   = (const float*)d_in[4];
    const float* U_f   = (const float*)d_in[5];
    const float* b_f   = (const float*)d_in[6];

    float* h  = (float*)d_out;
    float* xf = (float*)d_out;   // rows 0..24999 alias (proven R9/R10 ordering)

    char* p = (char*)d_ws;
    float* c   = (float*)p;  p += (size_t)NN*256*4;
    float* fc  = (float*)p;  p += (size_t)20480*256*4;
    f16* hthF = (f16*)p;     p += (size_t)20480*256*2;
    f16* htlF = (f16*)p;     p += (size_t)20480*256*2;
    f16* xhF = (f16*)p;      p += (size_t)NPAD*256*2;
    f16* xlF = (f16*)p;      p += (size_t)NPAD*256*2;
    f16* hhF = (f16*)p;      p += (size_t)NPAD*256*2;
    f16* hlF = (f16*)p;      p += (size_t)NPAD*256*2;
    f16* wih = (f16*)p;  p += 196608*2;
    f16* wil = (f16*)p;  p += 196608*2;
    f16* uih = (f16*)p;  p += 196608*2;
    f16* uil = (f16*)p;  p += 196608*2;
    f16* wfh = (f16*)p;  p += 65536*2;
    f16* wfl = (f16*)p;  p += 65536*2;
    f16* ufh = (f16*)p;  p += 65536*2;
    f16* ufl = (f16*)p;  p += 65536*2;

    split_w_iou<<<768, 256, 0, stream>>>(W_iou, wih, wil);
    split_w_iou<<<768, 256, 0, stream>>>(U_iou, uih, uil);
    split_w_f<<<256, 256, 0, stream>>>(W_f, wfh, wfl);
    split_w_f<<<256, 256, 0, stream>>>(U_f, ufh, ufl);
    split_x_FL<<<(int)(((long)NPAD*16 + 255)/256), 256, 0, stream>>>(x, xhF, xlF);

    const int S_[8] = {0, 1, 9, 73, 585, 4681, 37449, 200000};
    auto cdiv = [](int a, int b){ return (a + b - 1) / b; };

    // xf = x @ W_f + b_f for internal nodes (into d_out rows 0..24999)
    {
        int nt = cdiv(NINT, 128);
        f_gemm<0><<<nt*4, 512, 0, stream>>>(xhF, xlF, wfh, wfl, b_f,
            nullptr, nullptr, xf, 0, 0, NINT, 0);
    }
    // childless nodes 25000..199999: full LSTM, fc = 0
    {
        int tstart = 24960;                       // 128-aligned
        int nt = cdiv(NN - tstart, 128);
        iou_gemm<0><<<nt*8, 512, 0, stream>>>(xhF, xlF, nullptr, nullptr,
            wih, wil, nullptr, nullptr, b_iou, nullptr,
            c, h, hhF, hlF, tstart, NINT, NN);
    }
    // levels 5..0
    for (int l = 5; l >= 0; --l) {
        int ps = S_[l];
        int pe = (S_[l+1] < NINT) ? S_[l+1] : NINT;
        int cs = S_[l+1], ce = S_[l+2];
        int tsp = (ps >> 7) << 7;

        // child pass: acts = h FL ((node-1)-indexed)
        {
            int rstart = ((cs - 1) >> 7) << 7;
            int nt = cdiv((ce - 1) - rstart, 128);
            f_gemm<1><<<nt*4, 512, 0, stream>>>(hhF, hlF, ufh, ufl, nullptr,
                xf, c, fc, rstart, cs, ce, tsp);
        }
        // ht segment-sum -> FL (rows p - tsp)
        ht_sum_FL<<<cdiv((pe - ps)*64, 256), 256, 0, stream>>>(h, hthF, htlF, ps, pe, tsp);
        // parent pass: phase0 x@W_iou, phase1 ht@U_iou, + fc
        {
            int nt = cdiv(pe - tsp, 128);
            iou_gemm<1><<<nt*8, 512, 0, stream>>>(xhF, xlF, hthF, htlF,
                wih, wil, uih, uil, b_iou, fc,
                c, h, hhF, hlF, tsp, ps, pe);
        }
    }
}